// Round 11
// baseline (385.066 us; speedup 1.0000x reference)
//
#include <hip/hip_runtime.h>

// MeanShift++ dense-grid, distinct-bin formulation, v9 (region-tiled conv).
// Identity 1: ref pipeline == 5-tap triangular conv [1,2,3,2,1]^3 over per-bin
// sums/counts. Identity 2: result depends only on bin => per-step work is per
// OCCUPIED BIN; per-point state via 1-tap lookups.
// v9: occupancy mask is REGION-MAJOR (11 words per 7^3 region). k_compactR
// emits region-grouped item lists; k_convR loads an 11^3 halo tile into LDS
// with coalesced streams and taps from LDS (no bounds checks - halo covers
// edges). r10 model: conv cost ~ cache-lines per vmem instr; tiling makes the
// global traffic pure streams and moves taps to LDS.

constexpr float BW   = 0.1f;
constexpr float TOL2 = 1e-6f;            // (1e-3)^2
constexpr int DIM  = 112, OFF = 56;      // bins in [-56,55]; |x|<5.6 covered
constexpr int DIM2 = DIM * DIM;
constexpr int CELLS = DIM * DIM * DIM;   // 1,404,928
constexpr int RDIM = 16, RC = 7;         // 16^3 regions of 7^3 cells
constexpr int NREG = RDIM * RDIM * RDIM; // 4096
constexpr int RC3 = RC * RC * RC;        // 343
constexpr int RPW = 11;                  // mask words/region (352 bits >= 343)
constexpr int MWORDS = NREG * RPW;       // 45,056
constexpr int TD = RC + 4;               // 11 tile dim (halo 2)
constexpr int TCELLS = TD * TD * TD;     // 1331
constexpr int NB_A = 128, BLK = 256;
constexpr int NF = 2048;                 // k_convR grid
constexpr float FPS = 16777216.0f;       // 2^24 fixed-point scale
constexpr double FPSI = 1.0 / 16777216.0;

typedef float vf2 __attribute__((ext_vector_type(2)));

__device__ __forceinline__ int clampb(int v) { return v < 0 ? 0 : (v > DIM - 1 ? DIM - 1 : v); }
__device__ __forceinline__ int binf(float v) { return clampb((int)(v / BW) + OFF); }  // IEEE div+trunc == ref
__device__ __forceinline__ int flatb(int bx, int by, int bz) { return (bx * DIM + by) * DIM + bz; }
__device__ __forceinline__ int regOf(int bx, int by, int bz) {
    return ((bx / RC) * RDIM + (by / RC)) * RDIM + (bz / RC);
}
__device__ __forceinline__ int lcOf(int bx, int by, int bz) {
    return ((bx % RC) * RC + (by % RC)) * RC + (bz % RC);
}

__device__ __forceinline__ void pk_add(float* p, float a, float b) {
#if defined(__has_builtin) && __has_builtin(__builtin_amdgcn_global_atomic_fadd_v2f32)
    vf2 v = {a, b};
    __builtin_amdgcn_global_atomic_fadd_v2f32((vf2*)p, v);
#else
    atomicAdd(p, a);
    atomicAdd(p + 1, b);
#endif
}

// ---- pass A1: per-block region histogram (LDS) + streaming zero of grid B ----
__launch_bounds__(BLK)
__global__ void k_histA(const float* __restrict__ X, int n, int* __restrict__ blockHist,
                        float4* __restrict__ zeroB) {
    __shared__ int h[NREG];
    for (int i = threadIdx.x; i < NREG; i += blockDim.x) h[i] = 0;
    __syncthreads();
    int stride = gridDim.x * blockDim.x;
    for (int i = blockIdx.x * blockDim.x + threadIdx.x; i < n; i += stride) {
        float x = X[3 * i + 0], y = X[3 * i + 1], z = X[3 * i + 2];
        atomicAdd(&h[regOf(binf(x), binf(y), binf(z))], 1);
    }
    __syncthreads();
    for (int i = threadIdx.x; i < NREG; i += blockDim.x)
        blockHist[blockIdx.x * NREG + i] = h[i];
    for (int i = blockIdx.x * blockDim.x + threadIdx.x; i < CELLS; i += stride)
        zeroB[i] = make_float4(0.f, 0.f, 0.f, 0.f);
}

// ---- pass A2: per-region column scan over blocks ----
__global__ void k_colscan(int* __restrict__ blockHist, int* __restrict__ regionPS) {
    int r = blockIdx.x * blockDim.x + threadIdx.x;
    if (r >= NREG) return;
    int run = 0;
    for (int b = 0; b < NB_A; ++b) {
        int idx = b * NREG + r;
        int v = blockHist[idx];
        blockHist[idx] = run;
        run += v;
    }
    regionPS[r] = run;
}

// ---- pass A3: exclusive prefix over 4096 region totals ----
__launch_bounds__(1024)
__global__ void k_regprefix(int* __restrict__ regionPS) {
    __shared__ int buf[1024];
    int t = threadIdx.x;
    int v0 = regionPS[4 * t + 0], v1 = regionPS[4 * t + 1];
    int v2 = regionPS[4 * t + 2], v3 = regionPS[4 * t + 3];
    int s = v0 + v1 + v2 + v3;
    buf[t] = s;
    __syncthreads();
    for (int d = 1; d < 1024; d <<= 1) {
        int add = (t >= d) ? buf[t - d] : 0;
        __syncthreads();
        buf[t] += add;
        __syncthreads();
    }
    int excl = buf[t] - s;
    regionPS[4 * t + 0] = excl;
    regionPS[4 * t + 1] = excl + v0;
    regionPS[4 * t + 2] = excl + v0 + v1;
    regionPS[4 * t + 3] = excl + v0 + v1 + v2;
    if (t == 1023) regionPS[4096] = buf[1023];
}

// ---- pass A4: scatter points into region buckets + streaming zero of grid C ----
__launch_bounds__(BLK)
__global__ void k_scatterA(const float* __restrict__ X, int n,
                           const int* __restrict__ blockHist,
                           const int* __restrict__ regionPS,
                           float4* __restrict__ bucket, float4* __restrict__ zeroC) {
    __shared__ int cur[NREG];
    for (int i = threadIdx.x; i < NREG; i += blockDim.x) cur[i] = 0;
    __syncthreads();
    int stride = gridDim.x * blockDim.x;
    for (int i = blockIdx.x * blockDim.x + threadIdx.x; i < n; i += stride) {
        float x = X[3 * i + 0], y = X[3 * i + 1], z = X[3 * i + 2];
        int r = regOf(binf(x), binf(y), binf(z));
        int pos = regionPS[r] + blockHist[blockIdx.x * NREG + r] + atomicAdd(&cur[r], 1);
        bucket[pos] = make_float4(x, y, z, __int_as_float(i));
    }
    for (int i = blockIdx.x * blockDim.x + threadIdx.x; i < CELLS; i += stride)
        zeroC[i] = make_float4(0.f, 0.f, 0.f, 0.f);
}

// ---- pass B: one block/region — LDS int-atomic accumulate, store A, claim mask ----
__launch_bounds__(BLK)
__global__ void k_binB(const float4* __restrict__ bucket, const int* __restrict__ regionPS,
                       float4* __restrict__ A, unsigned* __restrict__ mask) {
    __shared__ unsigned long long aX[RC3], aY[RC3], aZ[RC3];
    __shared__ unsigned aC[RC3];
    __shared__ unsigned occ[RPW];
    int r = blockIdx.x;
    for (int c = threadIdx.x; c < RC3; c += blockDim.x) {
        aX[c] = 0ull; aY[c] = 0ull; aZ[c] = 0ull; aC[c] = 0u;
    }
    if (threadIdx.x < RPW) occ[threadIdx.x] = 0u;
    __syncthreads();
    int start = regionPS[r], end = regionPS[r + 1];
    for (int i = start + threadIdx.x; i < end; i += blockDim.x) {
        float4 p = bucket[i];
        int lc = lcOf(binf(p.x), binf(p.y), binf(p.z));
        atomicAdd(&aX[lc], (unsigned long long)(long long)rintf(p.x * FPS));
        atomicAdd(&aY[lc], (unsigned long long)(long long)rintf(p.y * FPS));
        atomicAdd(&aZ[lc], (unsigned long long)(long long)rintf(p.z * FPS));
        atomicAdd(&aC[lc], 1u);
    }
    __syncthreads();
    int rx = r / (RDIM * RDIM), ry = (r / RDIM) % RDIM, rz = r % RDIM;
    for (int c = threadIdx.x; c < RC3; c += blockDim.x) {
        if (aC[c] > 0u) {
            atomicOr(&occ[c >> 5], 1u << (c & 31));
            int bx = rx * RC + c / (RC * RC);
            int by = ry * RC + (c / RC) % RC;
            int bz = rz * RC + c % RC;
            A[flatb(bx, by, bz)] =
                make_float4((float)((double)(long long)aX[c] * FPSI),
                            (float)((double)(long long)aY[c] * FPSI),
                            (float)((double)(long long)aZ[c] * FPSI),
                            (float)aC[c]);
        }
    }
    __syncthreads();
    if (threadIdx.x < RPW) mask[r * RPW + threadIdx.x] = occ[threadIdx.x];
}

// ---- region-major mask -> region-grouped item list; clears mask ----
// one thread per region; 16 blocks x 256
__launch_bounds__(BLK)
__global__ void k_compactR(unsigned* __restrict__ mask, int* __restrict__ items,
                           int* __restrict__ regBase, int* __restrict__ regCnt,
                           int* __restrict__ actList, int* __restrict__ pActCnt,
                           int* __restrict__ pTot) {
    __shared__ int scan[BLK];
    __shared__ int sBase;
    int r = blockIdx.x * BLK + threadIdx.x;     // < NREG always (16*256)
    unsigned w[RPW];
    int cnt = 0;
    #pragma unroll
    for (int k = 0; k < RPW; ++k) {
        w[k] = mask[r * RPW + k];
        cnt += __popc(w[k]);
    }
    #pragma unroll
    for (int k = 0; k < RPW; ++k)
        if (w[k]) mask[r * RPW + k] = 0u;
    scan[threadIdx.x] = cnt;
    __syncthreads();
    for (int d = 1; d < BLK; d <<= 1) {
        int add = (threadIdx.x >= (unsigned)d) ? scan[threadIdx.x - d] : 0;
        __syncthreads();
        scan[threadIdx.x] += add;
        __syncthreads();
    }
    if (threadIdx.x == BLK - 1) {
        int tot = scan[BLK - 1];
        sBase = tot ? atomicAdd(pTot, tot) : 0;
    }
    __syncthreads();
    int base = sBase + scan[threadIdx.x] - cnt;
    regBase[r] = base;
    regCnt[r] = cnt;
    int rx = r / (RDIM * RDIM), ry = (r / RDIM) % RDIM, rz = r % RDIM;
    int idx = base;
    #pragma unroll
    for (int k = 0; k < RPW; ++k) {
        unsigned ww = w[k];
        while (ww) {
            int bpos = __ffs(ww) - 1;
            ww &= ww - 1;
            int lc = k * 32 + bpos;
            items[idx++] = flatb(rx * RC + lc / (RC * RC),
                                 ry * RC + (lc / RC) % RC,
                                 rz * RC + lc % RC);
        }
    }
    // active-region append (wave-aggregated)
    bool act = cnt > 0;
    unsigned long long m = __ballot(act);
    int lane = threadIdx.x & 63;
    if (m) {
        int leader = (int)__ffsll((long long)m) - 1;
        int ab;
        if (lane == leader) ab = atomicAdd(pActCnt, __popcll(m));
        ab = __shfl(ab, leader, 64);
        if (act) actList[ab + __popcll(m & ((1ull << lane) - 1))] = r;
    }
}

// ---- per-step kernel: region-tiled conv + misc segments ----
// Blocks [0,BC): one active region each (grid-stride): load 11^3 halo tile to
// LDS (coalesced), conv each of the region's items from LDS, write RE/IDX,
// scatter to tgt + claim region-major mask bit.
// Blocks [BC,NF): misc (upd / targeted grid clear).
__launch_bounds__(BLK)
__global__ void k_convR(
    const float4* __restrict__ src, const int* __restrict__ items,
    const int* __restrict__ regBase, const int* __restrict__ regCnt,
    const int* __restrict__ actList, const int* __restrict__ pActCnt,
    float4* __restrict__ REo, int* __restrict__ IDXo, float4* __restrict__ eposInit,
    float4* __restrict__ tgt, unsigned* __restrict__ clT,
    int updS, const float* __restrict__ X, int n,
    const float4* __restrict__ REp, const int* __restrict__ IDXp,
    const int* __restrict__ pM0, float4* __restrict__ epos,
    unsigned* __restrict__ notConv,
    const int* __restrict__ clearList, const int* __restrict__ pKc,
    float4* __restrict__ clearGrid, int lastStep) {
    __shared__ float4 tile[TCELLS];
    __shared__ unsigned sFlag;
    if (threadIdx.x == 0) sFlag = 0;
    __syncthreads();
    int AC = *pActCnt;
    int BC = AC < NF - 256 ? AC : NF - 256;
    const float t5[5] = {1.f, 2.f, 3.f, 2.f, 1.f};
    bool moved = false;

    if ((int)blockIdx.x < BC) {
        for (int ri = blockIdx.x; ri < AC; ri += BC) {
            int r = actList[ri];
            int rx = r / (RDIM * RDIM), ry = (r / RDIM) % RDIM, rz = r % RDIM;
            int gx0 = rx * RC - 2, gy0 = ry * RC - 2, gz0 = rz * RC - 2;
            for (int c = threadIdx.x; c < TCELLS; c += BLK) {
                int lx = c / (TD * TD), ly = (c / TD) % TD, lz = c % TD;
                int gx = gx0 + lx, gy = gy0 + ly, gz = gz0 + lz;
                float4 v = make_float4(0.f, 0.f, 0.f, 0.f);
                if ((unsigned)gx < (unsigned)DIM && (unsigned)gy < (unsigned)DIM &&
                    (unsigned)gz < (unsigned)DIM)
                    v = src[flatb(gx, gy, gz)];
                tile[c] = v;
            }
            __syncthreads();
            int base = regBase[r], cnt = regCnt[r];
            for (int q = threadIdx.x; q < cnt; q += BLK) {
                int item = base + q;
                int b = items[item];
                int bx = b / DIM2, rem = b % DIM2;
                int by = rem / DIM, bz = rem % DIM;
                int lx = bx - gx0, ly = by - gy0, lz = bz - gz0;  // in [2,8]
                float sx = 0.f, sy = 0.f, sz = 0.f, sc = 0.f;
                #pragma unroll
                for (int dx = 0; dx < 5; ++dx) {
                    float wx = t5[dx];
                    #pragma unroll
                    for (int dy = 0; dy < 5; ++dy) {
                        float wxy = wx * t5[dy];
                        const float4* row =
                            &tile[(lx + dx - 2) * (TD * TD) + (ly + dy - 2) * TD + (lz - 2)];
                        #pragma unroll
                        for (int dz = 0; dz < 5; ++dz) {
                            float w = wxy * t5[dz];
                            float4 e = row[dz];
                            sx = fmaf(w, e.x, sx);
                            sy = fmaf(w, e.y, sy);
                            sz = fmaf(w, e.z, sz);
                            sc = fmaf(w, e.w, sc);
                        }
                    }
                }
                float W = tile[lx * (TD * TD) + ly * TD + lz].w;  // center count
                float4 np = make_float4(sx / sc, sy / sc, sz / sc, W);
                REo[item] = np;
                IDXo[b] = item;
                if (eposInit) eposInit[item] = np;
                if (!lastStep) {
                    int nbx = binf(np.x), nby = binf(np.y), nbz = binf(np.z);
                    float* cell = (float*)&tgt[flatb(nbx, nby, nbz)];
                    pk_add(cell + 0, W * np.x, W * np.y);
                    pk_add(cell + 2, W * np.z, W);
                    int r2 = regOf(nbx, nby, nbz), lc2 = lcOf(nbx, nby, nbz);
                    atomicOr(&clT[r2 * RPW + (lc2 >> 5)], 1u << (lc2 & 31));
                }
            }
            __syncthreads();    // tile reuse
        }
    } else {
        int U = (updS > 0) ? (X ? n : *pM0) : 0;
        int CL = clearList ? *pKc : 0;
        int total = U + CL;
        bool done = false;
        if (updS > 1) {
            for (int t = 1; t < updS; ++t) done |= (notConv[t] == 0u);
        }
        int stride = (NF - BC) * blockDim.x;
        for (int idx = (blockIdx.x - BC) * blockDim.x + threadIdx.x; idx < total;
             idx += stride) {
            if (idx < U) {
                int e = idx;
                if (X) {  // per-point step-1 convergence: IDX1[bin0] -> REa
                    float x = X[3 * e + 0], y = X[3 * e + 1], z = X[3 * e + 2];
                    int j = IDXp[flatb(binf(x), binf(y), binf(z))];
                    float4 rr = REp[j];
                    float ex = rr.x - x, ey = rr.y - y, ez = rr.z - z;
                    moved |= (fmaf(ex, ex, fmaf(ey, ey, ez * ez)) > TOL2);
                } else if (!done) {  // per-entry update to step-updS position
                    float4 p = epos[e];
                    int j = IDXp[flatb(binf(p.x), binf(p.y), binf(p.z))];
                    float4 rr = REp[j];
                    float ex = rr.x - p.x, ey = rr.y - p.y, ez = rr.z - p.z;
                    moved |= (fmaf(ex, ex, fmaf(ey, ey, ez * ez)) > TOL2);
                    epos[e] = make_float4(rr.x, rr.y, rr.z, p.w);
                }
            } else {
                clearGrid[clearList[idx - U]] = make_float4(0.f, 0.f, 0.f, 0.f);
            }
        }
    }
    if (moved) sFlag = 1;
    __syncthreads();
    if (threadIdx.x == 0 && updS > 0 && sFlag) notConv[updS] = 1u;
}

// ---- finalize: per-entry final position table fpos[e] ----
__launch_bounds__(BLK)
__global__ void k_fin(const float4* __restrict__ REa, const int* __restrict__ IDXa,
                      const float4* __restrict__ epos, const int* __restrict__ pM0,
                      const unsigned* __restrict__ notConv, float4* __restrict__ fpos) {
    int M0 = *pM0;
    bool done = false;
    for (int t = 1; t <= 4; ++t) done |= (notConv[t] == 0u);
    for (int e = blockIdx.x * blockDim.x + threadIdx.x; e < M0;
         e += gridDim.x * blockDim.x) {
        float4 p = epos[e];
        if (!done) {
            float4 rr = REa[IDXa[flatb(binf(p.x), binf(p.y), binf(p.z))]];
            p.x = rr.x; p.y = rr.y; p.z = rr.z;
        }
        fpos[e] = p;
    }
}

// ---- per-point output: IDX1[bin0] -> fpos ----
__global__ void k_map(const float* __restrict__ X, int n, const int* __restrict__ IDX1,
                      const float4* __restrict__ fpos, float* __restrict__ out) {
    int i = blockIdx.x * blockDim.x + threadIdx.x;
    if (i >= n) return;
    float x = X[3 * i + 0], y = X[3 * i + 1], z = X[3 * i + 2];
    float4 p = fpos[IDX1[flatb(binf(x), binf(y), binf(z))]];
    out[3 * i + 0] = p.x;
    out[3 * i + 1] = p.y;
    out[3 * i + 2] = p.z;
}

extern "C" void kernel_launch(void* const* d_in, const int* in_sizes, int n_in,
                              void* d_out, int out_size, void* d_ws, size_t ws_size,
                              hipStream_t stream) {
    const float* X = (const float*)d_in[0];
    int n = in_sizes[0] / 3;

    // meta[0..7]=item totals cnt[s]; meta[8..15]=actCnt[s]; meta[16..23]=notConv
    char* ws = (char*)d_ws;
    int*      cnt     = (int*)ws;
    int*      actC    = (int*)ws + 8;
    unsigned* notConv = (unsigned*)ws + 16;
    size_t mB = (size_t)MWORDS * 4;          // 180,224
    size_t gB = (size_t)CELLS * 16;          // 22.47 MB
    unsigned* mA = (unsigned*)(ws + 256);
    unsigned* mBk = (unsigned*)(ws + 256 + mB);
    float4* A = (float4*)(ws + 256 + 2 * mB);
    float4* B = (float4*)((char*)A + gB);
    float4* C = (float4*)((char*)B + gB);
    int* IDX1 = (int*)((char*)C + gB);
    int* IDXa = IDX1 + CELLS;
    int* IDXb = IDXa + CELLS;
    float4* REa  = (float4*)(IDXb + CELLS);
    float4* REb  = REa + n;
    float4* epos = REb + n;
    int* E1 = (int*)(epos + n);
    int* E2 = E1 + n;
    int* E3 = E2 + n;
    int* rb1 = E3 + n;  int* rc1 = rb1 + NREG;
    int* rb2 = rc1 + NREG; int* rc2 = rb2 + NREG;
    int* rb3 = rc2 + NREG; int* rc3 = rb3 + NREG;
    int* act1 = rc3 + NREG;
    int* act2 = act1 + NREG;
    int* act3 = act2 + NREG;
    float4* bucket = (float4*)(act3 + NREG);
    int* blockHist = (int*)(bucket + n);
    int* regionPS  = blockHist + NB_A * NREG;   // NREG+1 ints

    hipMemsetAsync(ws, 0, 256 + 2 * mB + gB, stream);  // meta + masks + A

    k_histA<<<NB_A, BLK, 0, stream>>>(X, n, blockHist, B);
    k_colscan<<<NREG / BLK, BLK, 0, stream>>>(blockHist, regionPS);
    k_regprefix<<<1, 1024, 0, stream>>>(regionPS);
    k_scatterA<<<NB_A, BLK, 0, stream>>>(X, n, blockHist, regionPS, bucket, C);
    k_binB<<<NREG, BLK, 0, stream>>>(bucket, regionPS, A, mA);

    const int NCR = NREG / BLK;   // 16
    // step 1
    k_compactR<<<NCR, BLK, 0, stream>>>(mA, E1, rb1, rc1, act1, &actC[1], &cnt[1]);
    k_convR<<<NF, BLK, 0, stream>>>(A, E1, rb1, rc1, act1, &actC[1],
                                    REa, IDX1, epos, B, mBk,
                                    0, nullptr, n, nullptr, nullptr, nullptr, nullptr,
                                    notConv, nullptr, nullptr, nullptr, 0);
    // step 2: conv B; scatter->C claim mA; upd1 (X via IDX1/REa); clear A via E1
    k_compactR<<<NCR, BLK, 0, stream>>>(mBk, E2, rb2, rc2, act2, &actC[2], &cnt[2]);
    k_convR<<<NF, BLK, 0, stream>>>(B, E2, rb2, rc2, act2, &actC[2],
                                    REb, IDXb, nullptr, C, mA,
                                    1, X, n, REa, IDX1, &cnt[1], nullptr,
                                    notConv, E1, &cnt[1], A, 0);
    // step 3: conv C; scatter->A claim mB; upd2 (REb/IDXb); clear B via E2
    k_compactR<<<NCR, BLK, 0, stream>>>(mA, E3, rb3, rc3, act3, &actC[3], &cnt[3]);
    k_convR<<<NF, BLK, 0, stream>>>(C, E3, rb3, rc3, act3, &actC[3],
                                    REa, IDXa, nullptr, A, mBk,
                                    2, nullptr, n, REb, IDXb, &cnt[1], epos,
                                    notConv, E2, &cnt[2], B, 0);
    // step 4: conv A; scatter->B claim mA; upd3 (REa/IDXa); clear C via E3
    k_compactR<<<NCR, BLK, 0, stream>>>(mBk, E1, rb1, rc1, act1, &actC[4], &cnt[4]);
    k_convR<<<NF, BLK, 0, stream>>>(A, E1, rb1, rc1, act1, &actC[4],
                                    REb, IDXb, nullptr, B, mA,
                                    3, nullptr, n, REa, IDXa, &cnt[1], epos,
                                    notConv, E3, &cnt[3], C, 0);
    // step 5: conv B only; upd4 (REb/IDXb)
    k_compactR<<<NCR, BLK, 0, stream>>>(mA, E2, rb2, rc2, act2, &actC[5], &cnt[5]);
    k_convR<<<NF, BLK, 0, stream>>>(B, E2, rb2, rc2, act2, &actC[5],
                                    REa, IDXa, nullptr, nullptr, nullptr,
                                    4, nullptr, n, REb, IDXb, &cnt[1], epos,
                                    notConv, nullptr, nullptr, nullptr, 1);

    k_fin<<<256, BLK, 0, stream>>>(REa, IDXa, epos, &cnt[1], notConv, REb);
    k_map<<<(n + BLK - 1) / BLK, BLK, 0, stream>>>(X, n, IDX1, REb, (float*)d_out);
}

// Round 12
// 252.317 us; speedup vs baseline: 1.5261x; 1.5261x over previous
//
#include <hip/hip_runtime.h>

// MeanShift++ dense-grid, distinct-bin formulation, v10 = r10 (best, 253us)
// + XCD-aware conv chunk scheduling.
// Identity 1: ref pipeline == 5-tap triangular conv [1,2,3,2,1]^3 over per-bin
// sums/counts. Identity 2: result depends only on bin => per-step work is per
// OCCUPIED BIN; per-point state via 1-tap lookups.
// v10: conv chunks are bin-sorted; assign each XCD a CONTIGUOUS 1/8 of them
// (chunk = (blockIdx&7)*ceil(NC/8) + blockIdx>>3) instead of chunk=blockIdx,
// which round-robins neighbors across XCDs and makes every per-XCD L2 pull
// the whole working set (r9: FETCH 16MB/step vs ~2-4MB footprint = ~8x amp).
// r11's region-tile experiment REVERTED: tile bytes >> tap bytes at ~30
// items/region; FETCH rose to ~42MB/step and total regressed to 385us.

constexpr float BW   = 0.1f;
constexpr float TOL2 = 1e-6f;            // (1e-3)^2
constexpr int DIM  = 112, OFF = 56;      // bins in [-56,55]; |x|<5.6 covered
constexpr int DIM2 = DIM * DIM;
constexpr int CELLS = DIM * DIM * DIM;   // 1,404,928
constexpr int CLW = CELLS / 32;          // 43,904 mask words
constexpr int RDIM = 16, RC = 7;         // 16^3 regions of 7^3 cells
constexpr int NREG = RDIM * RDIM * RDIM; // 4096
constexpr int RC3 = RC * RC * RC;        // 343
constexpr int NB_A = 128, BLK = 256;
constexpr int NF = 2048;                 // k_fused grid
constexpr int IPB = 51;                  // conv items per block (51*5=255 thr)
constexpr float FPS = 16777216.0f;       // 2^24 fixed-point scale
constexpr double FPSI = 1.0 / 16777216.0;

typedef float vf2 __attribute__((ext_vector_type(2)));

__device__ __forceinline__ int clampb(int v) { return v < 0 ? 0 : (v > DIM - 1 ? DIM - 1 : v); }
__device__ __forceinline__ int binf(float v) { return clampb((int)(v / BW) + OFF); }  // IEEE div+trunc == ref
__device__ __forceinline__ int flatb(int bx, int by, int bz) { return (bx * DIM + by) * DIM + bz; }
__device__ __forceinline__ int regOf(int bx, int by, int bz) {
    return ((bx / RC) * RDIM + (by / RC)) * RDIM + (bz / RC);
}
__device__ __forceinline__ int lcOf(int bx, int by, int bz) {
    return ((bx % RC) * RC + (by % RC)) * RC + (bz % RC);
}

__device__ __forceinline__ void pk_add(float* p, float a, float b) {
#if defined(__has_builtin) && __has_builtin(__builtin_amdgcn_global_atomic_fadd_v2f32)
    vf2 v = {a, b};
    __builtin_amdgcn_global_atomic_fadd_v2f32((vf2*)p, v);
#else
    atomicAdd(p, a);
    atomicAdd(p + 1, b);
#endif
}

// ---- pass A1: per-block region histogram (LDS) + streaming zero of grid B ----
__launch_bounds__(BLK)
__global__ void k_histA(const float* __restrict__ X, int n, int* __restrict__ blockHist,
                        float4* __restrict__ zeroB) {
    __shared__ int h[NREG];
    for (int i = threadIdx.x; i < NREG; i += blockDim.x) h[i] = 0;
    __syncthreads();
    int stride = gridDim.x * blockDim.x;
    for (int i = blockIdx.x * blockDim.x + threadIdx.x; i < n; i += stride) {
        float x = X[3 * i + 0], y = X[3 * i + 1], z = X[3 * i + 2];
        atomicAdd(&h[regOf(binf(x), binf(y), binf(z))], 1);
    }
    __syncthreads();
    for (int i = threadIdx.x; i < NREG; i += blockDim.x)
        blockHist[blockIdx.x * NREG + i] = h[i];
    for (int i = blockIdx.x * blockDim.x + threadIdx.x; i < CELLS; i += stride)
        zeroB[i] = make_float4(0.f, 0.f, 0.f, 0.f);
}

// ---- pass A2: per-region column scan over blocks ----
__global__ void k_colscan(int* __restrict__ blockHist, int* __restrict__ regionPS) {
    int r = blockIdx.x * blockDim.x + threadIdx.x;
    if (r >= NREG) return;
    int run = 0;
    for (int b = 0; b < NB_A; ++b) {
        int idx = b * NREG + r;
        int v = blockHist[idx];
        blockHist[idx] = run;
        run += v;
    }
    regionPS[r] = run;
}

// ---- pass A3: exclusive prefix over 4096 region totals ----
__launch_bounds__(1024)
__global__ void k_regprefix(int* __restrict__ regionPS) {
    __shared__ int buf[1024];
    int t = threadIdx.x;
    int v0 = regionPS[4 * t + 0], v1 = regionPS[4 * t + 1];
    int v2 = regionPS[4 * t + 2], v3 = regionPS[4 * t + 3];
    int s = v0 + v1 + v2 + v3;
    buf[t] = s;
    __syncthreads();
    for (int d = 1; d < 1024; d <<= 1) {
        int add = (t >= d) ? buf[t - d] : 0;
        __syncthreads();
        buf[t] += add;
        __syncthreads();
    }
    int excl = buf[t] - s;
    regionPS[4 * t + 0] = excl;
    regionPS[4 * t + 1] = excl + v0;
    regionPS[4 * t + 2] = excl + v0 + v1;
    regionPS[4 * t + 3] = excl + v0 + v1 + v2;
    if (t == 1023) regionPS[4096] = buf[1023];
}

// ---- pass A4: scatter points into region buckets + streaming zero of grid C ----
__launch_bounds__(BLK)
__global__ void k_scatterA(const float* __restrict__ X, int n,
                           const int* __restrict__ blockHist,
                           const int* __restrict__ regionPS,
                           float4* __restrict__ bucket, float4* __restrict__ zeroC) {
    __shared__ int cur[NREG];
    for (int i = threadIdx.x; i < NREG; i += blockDim.x) cur[i] = 0;
    __syncthreads();
    int stride = gridDim.x * blockDim.x;
    for (int i = blockIdx.x * blockDim.x + threadIdx.x; i < n; i += stride) {
        float x = X[3 * i + 0], y = X[3 * i + 1], z = X[3 * i + 2];
        int r = regOf(binf(x), binf(y), binf(z));
        int pos = regionPS[r] + blockHist[blockIdx.x * NREG + r] + atomicAdd(&cur[r], 1);
        bucket[pos] = make_float4(x, y, z, __int_as_float(i));
    }
    for (int i = blockIdx.x * blockDim.x + threadIdx.x; i < CELLS; i += stride)
        zeroC[i] = make_float4(0.f, 0.f, 0.f, 0.f);
}

// ---- pass B: one block/region — LDS int-atomic accumulate, compact, PIdx ----
__launch_bounds__(BLK)
__global__ void k_binB(const float4* __restrict__ bucket, const int* __restrict__ regionPS,
                       float4* __restrict__ A, int* __restrict__ E0,
                       int* __restrict__ PIdx, int* __restrict__ gM0) {
    __shared__ unsigned long long aX[RC3], aY[RC3], aZ[RC3];
    __shared__ unsigned aC[RC3];
    __shared__ int cidx[RC3];
    __shared__ int cnt, cur, sBase;
    int r = blockIdx.x;
    for (int c = threadIdx.x; c < RC3; c += blockDim.x) {
        aX[c] = 0ull; aY[c] = 0ull; aZ[c] = 0ull; aC[c] = 0u;
    }
    if (threadIdx.x == 0) { cnt = 0; cur = 0; }
    __syncthreads();
    int start = regionPS[r], end = regionPS[r + 1];
    for (int i = start + threadIdx.x; i < end; i += blockDim.x) {
        float4 p = bucket[i];
        int lc = lcOf(binf(p.x), binf(p.y), binf(p.z));
        atomicAdd(&aX[lc], (unsigned long long)(long long)rintf(p.x * FPS));
        atomicAdd(&aY[lc], (unsigned long long)(long long)rintf(p.y * FPS));
        atomicAdd(&aZ[lc], (unsigned long long)(long long)rintf(p.z * FPS));
        atomicAdd(&aC[lc], 1u);
    }
    __syncthreads();
    int myc = 0;
    for (int c = threadIdx.x; c < RC3; c += blockDim.x)
        if (aC[c] > 0u) ++myc;
    if (myc) atomicAdd(&cnt, myc);
    __syncthreads();
    if (threadIdx.x == 0 && cnt > 0) sBase = atomicAdd(gM0, cnt);
    __syncthreads();
    int rx = r / (RDIM * RDIM), ry = (r / RDIM) % RDIM, rz = r % RDIM;
    for (int c = threadIdx.x; c < RC3; c += blockDim.x) {
        if (aC[c] > 0u) {
            int idx = sBase + atomicAdd(&cur, 1);
            cidx[c] = idx;
            int bx = rx * RC + c / (RC * RC);
            int by = ry * RC + (c / RC) % RC;
            int bz = rz * RC + c % RC;
            int b = flatb(bx, by, bz);
            E0[idx] = b;
            A[b] = make_float4((float)((double)(long long)aX[c] * FPSI),
                               (float)((double)(long long)aY[c] * FPSI),
                               (float)((double)(long long)aZ[c] * FPSI),
                               (float)aC[c]);
        }
    }
    __syncthreads();
    for (int i = start + threadIdx.x; i < end; i += blockDim.x) {
        float4 p = bucket[i];
        int lc = lcOf(binf(p.x), binf(p.y), binf(p.z));
        PIdx[__float_as_int(p.w)] = cidx[lc];
    }
}

// ---- mask -> bin-sorted list (block scan, 1 atomic/block), clears mask ----
__launch_bounds__(BLK)
__global__ void k_compactM(unsigned* __restrict__ mask, int* __restrict__ listOut,
                           int* __restrict__ pKout) {
    __shared__ int scan[BLK];
    __shared__ int sBase;
    int i = blockIdx.x * blockDim.x + threadIdx.x;
    unsigned w = (i < CLW) ? mask[i] : 0u;
    if (i < CLW && w) mask[i] = 0u;
    int c = __popc(w);
    scan[threadIdx.x] = c;
    __syncthreads();
    for (int d = 1; d < BLK; d <<= 1) {
        int add = (threadIdx.x >= (unsigned)d) ? scan[threadIdx.x - d] : 0;
        __syncthreads();
        scan[threadIdx.x] += add;
        __syncthreads();
    }
    if (threadIdx.x == BLK - 1) {
        int tot = scan[BLK - 1];
        sBase = tot ? atomicAdd(pKout, tot) : 0;
    }
    __syncthreads();
    int base = sBase + scan[threadIdx.x] - c;
    int bb = i * 32;
    while (w) {
        int b = __ffs(w) - 1;
        listOut[base++] = bb + b;
        w &= w - 1;
    }
}

// ---- fused per-step kernel ----
// Blocks [0, BC): conv, 51 items/block-chunk, 5 threads/item (one dx-plane),
//   row-contiguous taps, LDS reduce; finalize+scatter+claim by lanes 0..50.
//   Chunk order is XCD-aware: each XCD gets a contiguous 1/8 of bin-sorted
//   chunks so its private L2 holds only 1/8 of the grid footprint.
// Blocks [BC, NF): grid-stride misc (upd / targeted clear).
__launch_bounds__(BLK)
__global__ void k_fused(
    const float4* __restrict__ src, const int* __restrict__ list, const int* __restrict__ pK,
    float4* __restrict__ REo, int* __restrict__ IDXo, float4* __restrict__ eposInit,
    float4* __restrict__ tgt, unsigned* __restrict__ clT,
    int updS, const float* __restrict__ X, int n, const int* __restrict__ PIdx,
    const float4* __restrict__ REp, const int* __restrict__ IDXp,
    const int* __restrict__ pM0, float4* __restrict__ epos,
    unsigned* __restrict__ notConv,
    const int* __restrict__ clearList, const int* __restrict__ pKc,
    float4* __restrict__ clearGrid, int lastStep) {
    __shared__ float4 sh[BLK];
    __shared__ unsigned sFlag;
    if (threadIdx.x == 0) sFlag = 0;
    __syncthreads();
    int K = *pK;
    int NC = (K + IPB - 1) / IPB;        // total conv chunks
    int BC = NC;
    if (BC > NF - 256) BC = NF - 256;    // always keep misc blocks
    const float t5[5] = {1.f, 2.f, 3.f, 2.f, 1.f};
    bool moved = false;

    if ((int)blockIdx.x < BC) {
        // ---------------- conv blocks ----------------
        // XCD-aware chunk range: dispatch round-robins blockIdx across 8 XCDs;
        // give xcd k the contiguous chunks [k*cpx, (k+1)*cpx).
        int first, last, step;
        if (BC >= 64) {
            int xcd = blockIdx.x & 7, loc = blockIdx.x >> 3;
            int cpx = (NC + 7) >> 3;                 // chunks per XCD
            int bpx = ((BC - 1 - xcd) >> 3) + 1;     // blocks on this XCD
            first = xcd * cpx + loc;
            last = (xcd + 1) * cpx; if (last > NC) last = NC;
            step = bpx;
        } else {
            first = blockIdx.x; last = NC; step = BC;
        }
        for (int ib = first; ib < last; ib += step) {
            int li = threadIdx.x / 5;
            int dx = threadIdx.x % 5;
            int item = ib * IPB + li;
            float4 part = make_float4(0.f, 0.f, 0.f, 0.f);
            if (li < IPB && item < K) {
                int b = list[item];
                int bx = b / DIM2, rem = b % DIM2;
                int by = rem / DIM, bz = rem % DIM;
                int ix = bx + dx - 2;
                if ((unsigned)ix < (unsigned)DIM) {
                    float wx = t5[dx];
                    if (by >= 2 && by <= DIM - 3 && bz >= 2 && bz <= DIM - 3) {
                        #pragma unroll
                        for (int dy = 0; dy < 5; ++dy) {
                            float wxy = wx * t5[dy];
                            const float4* row = src + flatb(ix, by + dy - 2, bz - 2);
                            #pragma unroll
                            for (int dz = 0; dz < 5; ++dz) {
                                float w = wxy * t5[dz];
                                float4 e = row[dz];
                                part.x = fmaf(w, e.x, part.x);
                                part.y = fmaf(w, e.y, part.y);
                                part.z = fmaf(w, e.z, part.z);
                                part.w = fmaf(w, e.w, part.w);
                            }
                        }
                    } else {
                        for (int dy = 0; dy < 5; ++dy) {
                            int iy = by + dy - 2;
                            if ((unsigned)iy >= (unsigned)DIM) continue;
                            float wxy = wx * t5[dy];
                            for (int dz = 0; dz < 5; ++dz) {
                                int iz = bz + dz - 2;
                                if ((unsigned)iz >= (unsigned)DIM) continue;
                                float w = wxy * t5[dz];
                                float4 e = src[flatb(ix, iy, iz)];
                                part.x = fmaf(w, e.x, part.x);
                                part.y = fmaf(w, e.y, part.y);
                                part.z = fmaf(w, e.z, part.z);
                                part.w = fmaf(w, e.w, part.w);
                            }
                        }
                    }
                }
            }
            sh[threadIdx.x] = part;
            __syncthreads();
            if (threadIdx.x < IPB) {
                int item2 = ib * IPB + threadIdx.x;
                if (item2 < K) {
                    int base5 = threadIdx.x * 5;
                    float4 a0 = sh[base5 + 0], a1 = sh[base5 + 1], a2 = sh[base5 + 2];
                    float4 a3 = sh[base5 + 3], a4 = sh[base5 + 4];
                    float sx = a0.x + a1.x + a2.x + a3.x + a4.x;
                    float sy = a0.y + a1.y + a2.y + a3.y + a4.y;
                    float sz = a0.z + a1.z + a2.z + a3.z + a4.z;
                    float sc = a0.w + a1.w + a2.w + a3.w + a4.w;
                    int b = list[item2];
                    float W = src[b].w;     // center count (occupied => sc>0)
                    float4 np = make_float4(sx / sc, sy / sc, sz / sc, W);
                    REo[item2] = np;
                    IDXo[b] = item2;
                    if (eposInit) eposInit[item2] = np;
                    if (!lastStep) {
                        int bn = flatb(binf(np.x), binf(np.y), binf(np.z));
                        float* cell = (float*)&tgt[bn];
                        pk_add(cell + 0, W * np.x, W * np.y);
                        pk_add(cell + 2, W * np.z, W);
                        atomicOr(&clT[(unsigned)bn >> 5], 1u << (bn & 31));
                    }
                }
            }
            __syncthreads();    // sh reuse
        }
    } else {
        // ---------------- misc blocks ----------------
        int U = (updS > 0) ? (X ? n : *pM0) : 0;
        int CL = clearList ? *pKc : 0;
        int total = U + CL;
        bool done = false;
        if (updS > 1) {
            for (int t = 1; t < updS; ++t) done |= (notConv[t] == 0u);
        }
        int stride = (NF - BC) * blockDim.x;
        for (int idx = (blockIdx.x - BC) * blockDim.x + threadIdx.x; idx < total;
             idx += stride) {
            if (idx < U) {
                int e = idx;
                if (X) {  // per-point step-1 convergence via PIdx
                    float x = X[3 * e + 0], y = X[3 * e + 1], z = X[3 * e + 2];
                    float4 rr = REp[PIdx[e]];
                    float ex = rr.x - x, ey = rr.y - y, ez = rr.z - z;
                    moved |= (fmaf(ex, ex, fmaf(ey, ey, ez * ez)) > TOL2);
                } else if (!done) {  // per-entry update to step-updS position
                    float4 p = epos[e];
                    int j = IDXp[flatb(binf(p.x), binf(p.y), binf(p.z))];
                    float4 rr = REp[j];
                    float ex = rr.x - p.x, ey = rr.y - p.y, ez = rr.z - p.z;
                    moved |= (fmaf(ex, ex, fmaf(ey, ey, ez * ez)) > TOL2);
                    epos[e] = make_float4(rr.x, rr.y, rr.z, p.w);
                }
            } else {
                clearGrid[clearList[idx - U]] = make_float4(0.f, 0.f, 0.f, 0.f);
            }
        }
    }
    if (moved) sFlag = 1;
    __syncthreads();
    if (threadIdx.x == 0 && updS > 0 && sFlag) notConv[updS] = 1u;
}

// ---- finalize: per-entry final position table fpos[e] ----
__launch_bounds__(BLK)
__global__ void k_fin(const float4* __restrict__ REa, const int* __restrict__ IDXa,
                      const float4* __restrict__ epos, const int* __restrict__ pM0,
                      const unsigned* __restrict__ notConv, float4* __restrict__ fpos) {
    int M0 = *pM0;
    bool done = false;
    for (int t = 1; t <= 4; ++t) done |= (notConv[t] == 0u);
    for (int e = blockIdx.x * blockDim.x + threadIdx.x; e < M0;
         e += gridDim.x * blockDim.x) {
        float4 p = epos[e];
        if (!done) {
            float4 rr = REa[IDXa[flatb(binf(p.x), binf(p.y), binf(p.z))]];
            p.x = rr.x; p.y = rr.y; p.z = rr.z;
        }
        fpos[e] = p;
    }
}

// ---- per-point output: single gather through fpos via PIdx ----
__global__ void k_map(const int* __restrict__ PIdx, int n, const float4* __restrict__ fpos,
                      float* __restrict__ out) {
    int i = blockIdx.x * blockDim.x + threadIdx.x;
    if (i >= n) return;
    float4 p = fpos[PIdx[i]];
    out[3 * i + 0] = p.x;
    out[3 * i + 1] = p.y;
    out[3 * i + 2] = p.z;
}

extern "C" void kernel_launch(void* const* d_in, const int* in_sizes, int n_in,
                              void* d_out, int out_size, void* d_ws, size_t ws_size,
                              hipStream_t stream) {
    const float* X = (const float*)d_in[0];
    int n = in_sizes[0] / 3;

    char* ws = (char*)d_ws;
    int*      cnt     = (int*)ws;        // cnt[1..5] list sizes
    unsigned* notConv = (unsigned*)(ws + 32);
    size_t mB = (size_t)CLW * 4;
    size_t gB = (size_t)CELLS * 16;
    unsigned* m0 = (unsigned*)(ws + 256);
    unsigned* m1 = (unsigned*)(ws + 256 + mB);
    float4* A = (float4*)(ws + 256 + 2 * mB);
    float4* B = (float4*)((char*)A + gB);
    float4* C = (float4*)((char*)B + gB);
    int* IDXa = (int*)((char*)C + gB);
    int* IDXb = IDXa + CELLS;
    float4* REa  = (float4*)(IDXb + CELLS);
    float4* REb  = REa + n;
    float4* epos = REb + n;
    int* E0   = (int*)(epos + n);
    int* La   = E0 + n;
    int* Lb   = La + n;
    int* Lc   = Lb + n;
    int* Ld   = Lc + n;
    int* PIdx = Ld + n;
    float4* bucket = (float4*)(PIdx + n);
    int* blockHist = (int*)(bucket + n);
    int* regionPS  = blockHist + NB_A * NREG;

    hipMemsetAsync(ws, 0, 256 + 2 * mB + gB, stream);  // meta+masks+A

    const int NCM = (CLW + BLK - 1) / BLK;   // compactM blocks

    k_histA<<<NB_A, BLK, 0, stream>>>(X, n, blockHist, B);
    k_colscan<<<NREG / BLK, BLK, 0, stream>>>(blockHist, regionPS);
    k_regprefix<<<1, 1024, 0, stream>>>(regionPS);
    k_scatterA<<<NB_A, BLK, 0, stream>>>(X, n, blockHist, regionPS, bucket, C);
    k_binB<<<NREG, BLK, 0, stream>>>(bucket, regionPS, A, E0, PIdx, &cnt[1]);

    // F1: conv A/E0 -> REa/IDXa (+epos init); scatter->B claim m0
    k_fused<<<NF, BLK, 0, stream>>>(A, E0, &cnt[1], REa, IDXa, epos,
                                    B, m0,
                                    0, nullptr, n, nullptr, nullptr, nullptr, nullptr,
                                    nullptr, notConv, nullptr, nullptr, nullptr, 0);
    // sorted list for step 2; clears m0 (free for F3)
    k_compactM<<<NCM, BLK, 0, stream>>>(m0, La, &cnt[2]);
    // F2: conv B/La -> REb/IDXb; scatter->C claim m1; upd1 via PIdx (REa); clear A via E0
    k_fused<<<NF, BLK, 0, stream>>>(B, La, &cnt[2], REb, IDXb, nullptr,
                                    C, m1,
                                    1, X, n, PIdx, REa, IDXa, &cnt[1], nullptr,
                                    notConv, E0, &cnt[1], A, 0);
    k_compactM<<<NCM, BLK, 0, stream>>>(m1, Lb, &cnt[3]);
    // F3: conv C/Lb -> REa/IDXa; scatter->A claim m0; upd2 (REb/IDXb); clear B via La
    k_fused<<<NF, BLK, 0, stream>>>(C, Lb, &cnt[3], REa, IDXa, nullptr,
                                    A, m0,
                                    2, nullptr, n, nullptr, REb, IDXb, &cnt[1], epos,
                                    notConv, La, &cnt[2], B, 0);
    k_compactM<<<NCM, BLK, 0, stream>>>(m0, Lc, &cnt[4]);
    // F4: conv A/Lc -> REb/IDXb; scatter->B claim m1; upd3 (REa/IDXa)
    k_fused<<<NF, BLK, 0, stream>>>(A, Lc, &cnt[4], REb, IDXb, nullptr,
                                    B, m1,
                                    3, nullptr, n, nullptr, REa, IDXa, &cnt[1], epos,
                                    notConv, nullptr, nullptr, nullptr, 0);
    k_compactM<<<NCM, BLK, 0, stream>>>(m1, Ld, &cnt[5]);
    // F5: conv B/Ld -> REa/IDXa (conv only); upd4 (REb/IDXb)
    k_fused<<<NF, BLK, 0, stream>>>(B, Ld, &cnt[5], REa, IDXa, nullptr,
                                    nullptr, nullptr,
                                    4, nullptr, n, nullptr, REb, IDXb, &cnt[1], epos,
                                    notConv, nullptr, nullptr, nullptr, 1);

    k_fin<<<256, BLK, 0, stream>>>(REa, IDXa, epos, &cnt[1], notConv, REb);
    k_map<<<(n + BLK - 1) / BLK, BLK, 0, stream>>>(PIdx, n, REb, (float*)d_out);
}

// Round 14
// 248.237 us; speedup vs baseline: 1.5512x; 1.0164x over previous
//
#include <hip/hip_runtime.h>

// MeanShift++ dense-grid, distinct-bin formulation, v12 = r12 (252us)
// + CORRECTED wave-segmented scatter dedup + A-zero fused into histA.
// Identity 1: ref pipeline == 5-tap triangular conv [1,2,3,2,1]^3 over per-bin
// sums/counts. Identity 2: result depends only on bin => per-step work is per
// OCCUPIED BIN; per-point state via 1-tap lookups.
// r13 BUG (absmax 0.55): segmented scan keyed on bn EQUALITY double-counted
// when equal target bins were non-adjacent ([t5,t7,t5]). v12 uses the proper
// head-flag segmented scan: runs = maximal ADJACENT equal-key spans; only run
// leaders issue pk_add/atomicOr; non-adjacent duplicates flush separately
// (correct, merely less dedup).
// Dead levers (measured): region-LDS-tile conv (r11, -52%), flattened-tap
// 8-lane conv (r8, -78%), XCD chunk partition (r12, neutral; kept, harmless).

constexpr float BW   = 0.1f;
constexpr float TOL2 = 1e-6f;            // (1e-3)^2
constexpr int DIM  = 112, OFF = 56;      // bins in [-56,55]; |x|<5.6 covered
constexpr int DIM2 = DIM * DIM;
constexpr int CELLS = DIM * DIM * DIM;   // 1,404,928
constexpr int CLW = CELLS / 32;          // 43,904 mask words
constexpr int RDIM = 16, RC = 7;         // 16^3 regions of 7^3 cells
constexpr int NREG = RDIM * RDIM * RDIM; // 4096
constexpr int RC3 = RC * RC * RC;        // 343
constexpr int NB_A = 128, BLK = 256;
constexpr int NF = 2048;                 // k_fused grid
constexpr int IPB = 51;                  // conv items per block (51*5=255 thr)
constexpr float FPS = 16777216.0f;       // 2^24 fixed-point scale
constexpr double FPSI = 1.0 / 16777216.0;

typedef float vf2 __attribute__((ext_vector_type(2)));

__device__ __forceinline__ int clampb(int v) { return v < 0 ? 0 : (v > DIM - 1 ? DIM - 1 : v); }
__device__ __forceinline__ int binf(float v) { return clampb((int)(v / BW) + OFF); }  // IEEE div+trunc == ref
__device__ __forceinline__ int flatb(int bx, int by, int bz) { return (bx * DIM + by) * DIM + bz; }
__device__ __forceinline__ int regOf(int bx, int by, int bz) {
    return ((bx / RC) * RDIM + (by / RC)) * RDIM + (bz / RC);
}
__device__ __forceinline__ int lcOf(int bx, int by, int bz) {
    return ((bx % RC) * RC + (by % RC)) * RC + (bz % RC);
}

__device__ __forceinline__ void pk_add(float* p, float a, float b) {
#if defined(__has_builtin) && __has_builtin(__builtin_amdgcn_global_atomic_fadd_v2f32)
    vf2 v = {a, b};
    __builtin_amdgcn_global_atomic_fadd_v2f32((vf2*)p, v);
#else
    atomicAdd(p, a);
    atomicAdd(p + 1, b);
#endif
}

// ---- pass A1: per-block region histogram (LDS) + streaming zero of grids A,B ----
__launch_bounds__(BLK)
__global__ void k_histA(const float* __restrict__ X, int n, int* __restrict__ blockHist,
                        float4* __restrict__ zeroA, float4* __restrict__ zeroB) {
    __shared__ int h[NREG];
    for (int i = threadIdx.x; i < NREG; i += blockDim.x) h[i] = 0;
    __syncthreads();
    int stride = gridDim.x * blockDim.x;
    for (int i = blockIdx.x * blockDim.x + threadIdx.x; i < n; i += stride) {
        float x = X[3 * i + 0], y = X[3 * i + 1], z = X[3 * i + 2];
        atomicAdd(&h[regOf(binf(x), binf(y), binf(z))], 1);
    }
    __syncthreads();
    for (int i = threadIdx.x; i < NREG; i += blockDim.x)
        blockHist[blockIdx.x * NREG + i] = h[i];
    for (int i = blockIdx.x * blockDim.x + threadIdx.x; i < CELLS; i += stride) {
        zeroA[i] = make_float4(0.f, 0.f, 0.f, 0.f);
        zeroB[i] = make_float4(0.f, 0.f, 0.f, 0.f);
    }
}

// ---- pass A2: per-region column scan over blocks ----
__global__ void k_colscan(int* __restrict__ blockHist, int* __restrict__ regionPS) {
    int r = blockIdx.x * blockDim.x + threadIdx.x;
    if (r >= NREG) return;
    int run = 0;
    for (int b = 0; b < NB_A; ++b) {
        int idx = b * NREG + r;
        int v = blockHist[idx];
        blockHist[idx] = run;
        run += v;
    }
    regionPS[r] = run;
}

// ---- pass A3: exclusive prefix over 4096 region totals ----
__launch_bounds__(1024)
__global__ void k_regprefix(int* __restrict__ regionPS) {
    __shared__ int buf[1024];
    int t = threadIdx.x;
    int v0 = regionPS[4 * t + 0], v1 = regionPS[4 * t + 1];
    int v2 = regionPS[4 * t + 2], v3 = regionPS[4 * t + 3];
    int s = v0 + v1 + v2 + v3;
    buf[t] = s;
    __syncthreads();
    for (int d = 1; d < 1024; d <<= 1) {
        int add = (t >= d) ? buf[t - d] : 0;
        __syncthreads();
        buf[t] += add;
        __syncthreads();
    }
    int excl = buf[t] - s;
    regionPS[4 * t + 0] = excl;
    regionPS[4 * t + 1] = excl + v0;
    regionPS[4 * t + 2] = excl + v0 + v1;
    regionPS[4 * t + 3] = excl + v0 + v1 + v2;
    if (t == 1023) regionPS[4096] = buf[1023];
}

// ---- pass A4: scatter points into region buckets + streaming zero of grid C ----
__launch_bounds__(BLK)
__global__ void k_scatterA(const float* __restrict__ X, int n,
                           const int* __restrict__ blockHist,
                           const int* __restrict__ regionPS,
                           float4* __restrict__ bucket, float4* __restrict__ zeroC) {
    __shared__ int cur[NREG];
    for (int i = threadIdx.x; i < NREG; i += blockDim.x) cur[i] = 0;
    __syncthreads();
    int stride = gridDim.x * blockDim.x;
    for (int i = blockIdx.x * blockDim.x + threadIdx.x; i < n; i += stride) {
        float x = X[3 * i + 0], y = X[3 * i + 1], z = X[3 * i + 2];
        int r = regOf(binf(x), binf(y), binf(z));
        int pos = regionPS[r] + blockHist[blockIdx.x * NREG + r] + atomicAdd(&cur[r], 1);
        bucket[pos] = make_float4(x, y, z, __int_as_float(i));
    }
    for (int i = blockIdx.x * blockDim.x + threadIdx.x; i < CELLS; i += stride)
        zeroC[i] = make_float4(0.f, 0.f, 0.f, 0.f);
}

// ---- pass B: one block/region — LDS int-atomic accumulate, compact, PIdx ----
__launch_bounds__(BLK)
__global__ void k_binB(const float4* __restrict__ bucket, const int* __restrict__ regionPS,
                       float4* __restrict__ A, int* __restrict__ E0,
                       int* __restrict__ PIdx, int* __restrict__ gM0) {
    __shared__ unsigned long long aX[RC3], aY[RC3], aZ[RC3];
    __shared__ unsigned aC[RC3];
    __shared__ int cidx[RC3];
    __shared__ int cnt, cur, sBase;
    int r = blockIdx.x;
    for (int c = threadIdx.x; c < RC3; c += blockDim.x) {
        aX[c] = 0ull; aY[c] = 0ull; aZ[c] = 0ull; aC[c] = 0u;
    }
    if (threadIdx.x == 0) { cnt = 0; cur = 0; }
    __syncthreads();
    int start = regionPS[r], end = regionPS[r + 1];
    for (int i = start + threadIdx.x; i < end; i += blockDim.x) {
        float4 p = bucket[i];
        int lc = lcOf(binf(p.x), binf(p.y), binf(p.z));
        atomicAdd(&aX[lc], (unsigned long long)(long long)rintf(p.x * FPS));
        atomicAdd(&aY[lc], (unsigned long long)(long long)rintf(p.y * FPS));
        atomicAdd(&aZ[lc], (unsigned long long)(long long)rintf(p.z * FPS));
        atomicAdd(&aC[lc], 1u);
    }
    __syncthreads();
    int myc = 0;
    for (int c = threadIdx.x; c < RC3; c += blockDim.x)
        if (aC[c] > 0u) ++myc;
    if (myc) atomicAdd(&cnt, myc);
    __syncthreads();
    if (threadIdx.x == 0 && cnt > 0) sBase = atomicAdd(gM0, cnt);
    __syncthreads();
    int rx = r / (RDIM * RDIM), ry = (r / RDIM) % RDIM, rz = r % RDIM;
    for (int c = threadIdx.x; c < RC3; c += blockDim.x) {
        if (aC[c] > 0u) {
            int idx = sBase + atomicAdd(&cur, 1);
            cidx[c] = idx;
            int bx = rx * RC + c / (RC * RC);
            int by = ry * RC + (c / RC) % RC;
            int bz = rz * RC + c % RC;
            int b = flatb(bx, by, bz);
            E0[idx] = b;
            A[b] = make_float4((float)((double)(long long)aX[c] * FPSI),
                               (float)((double)(long long)aY[c] * FPSI),
                               (float)((double)(long long)aZ[c] * FPSI),
                               (float)aC[c]);
        }
    }
    __syncthreads();
    for (int i = start + threadIdx.x; i < end; i += blockDim.x) {
        float4 p = bucket[i];
        int lc = lcOf(binf(p.x), binf(p.y), binf(p.z));
        PIdx[__float_as_int(p.w)] = cidx[lc];
    }
}

// ---- mask -> bin-sorted list (block scan, 1 atomic/block), clears mask ----
__launch_bounds__(BLK)
__global__ void k_compactM(unsigned* __restrict__ mask, int* __restrict__ listOut,
                           int* __restrict__ pKout) {
    __shared__ int scan[BLK];
    __shared__ int sBase;
    int i = blockIdx.x * blockDim.x + threadIdx.x;
    unsigned w = (i < CLW) ? mask[i] : 0u;
    if (i < CLW && w) mask[i] = 0u;
    int c = __popc(w);
    scan[threadIdx.x] = c;
    __syncthreads();
    for (int d = 1; d < BLK; d <<= 1) {
        int add = (threadIdx.x >= (unsigned)d) ? scan[threadIdx.x - d] : 0;
        __syncthreads();
        scan[threadIdx.x] += add;
        __syncthreads();
    }
    if (threadIdx.x == BLK - 1) {
        int tot = scan[BLK - 1];
        sBase = tot ? atomicAdd(pKout, tot) : 0;
    }
    __syncthreads();
    int base = sBase + scan[threadIdx.x] - c;
    int bb = i * 32;
    while (w) {
        int b = __ffs(w) - 1;
        listOut[base++] = bb + b;
        w &= w - 1;
    }
}

// ---- fused per-step kernel ----
// Blocks [0, BC): conv, 51 items/chunk, 5 threads/item (one dx-plane each),
//   row-contiguous taps, LDS reduce; finalize by wave 0 with head-flag
//   segmented dedup (adjacent equal targets merge; leaders issue atomics).
// Blocks [BC, NF): grid-stride misc (upd / targeted clear).
__launch_bounds__(BLK)
__global__ void k_fused(
    const float4* __restrict__ src, const int* __restrict__ list, const int* __restrict__ pK,
    float4* __restrict__ REo, int* __restrict__ IDXo, float4* __restrict__ eposInit,
    float4* __restrict__ tgt, unsigned* __restrict__ clT,
    int updS, const float* __restrict__ X, int n, const int* __restrict__ PIdx,
    const float4* __restrict__ REp, const int* __restrict__ IDXp,
    const int* __restrict__ pM0, float4* __restrict__ epos,
    unsigned* __restrict__ notConv,
    const int* __restrict__ clearList, const int* __restrict__ pKc,
    float4* __restrict__ clearGrid, int lastStep) {
    __shared__ float4 sh[BLK];
    __shared__ unsigned sFlag;
    if (threadIdx.x == 0) sFlag = 0;
    __syncthreads();
    int K = *pK;
    int NC = (K + IPB - 1) / IPB;        // total conv chunks
    int BC = NC;
    if (BC > NF - 256) BC = NF - 256;    // always keep misc blocks
    const float t5[5] = {1.f, 2.f, 3.f, 2.f, 1.f};
    bool moved = false;

    if ((int)blockIdx.x < BC) {
        // ---------------- conv blocks ----------------
        int first, last, step;
        if (BC >= 64) {   // XCD-contiguous chunk ranges (measured neutral, kept)
            int xcd = blockIdx.x & 7, loc = blockIdx.x >> 3;
            int cpx = (NC + 7) >> 3;
            int bpx = ((BC - 1 - xcd) >> 3) + 1;
            first = xcd * cpx + loc;
            last = (xcd + 1) * cpx; if (last > NC) last = NC;
            step = bpx;
        } else {
            first = blockIdx.x; last = NC; step = BC;
        }
        for (int ib = first; ib < last; ib += step) {
            int li = threadIdx.x / 5;
            int dx = threadIdx.x % 5;
            int item = ib * IPB + li;
            float4 part = make_float4(0.f, 0.f, 0.f, 0.f);
            if (li < IPB && item < K) {
                int b = list[item];
                int bx = b / DIM2, rem = b % DIM2;
                int by = rem / DIM, bz = rem % DIM;
                int ix = bx + dx - 2;
                if ((unsigned)ix < (unsigned)DIM) {
                    float wx = t5[dx];
                    if (by >= 2 && by <= DIM - 3 && bz >= 2 && bz <= DIM - 3) {
                        #pragma unroll
                        for (int dy = 0; dy < 5; ++dy) {
                            float wxy = wx * t5[dy];
                            const float4* row = src + flatb(ix, by + dy - 2, bz - 2);
                            #pragma unroll
                            for (int dz = 0; dz < 5; ++dz) {
                                float w = wxy * t5[dz];
                                float4 e = row[dz];
                                part.x = fmaf(w, e.x, part.x);
                                part.y = fmaf(w, e.y, part.y);
                                part.z = fmaf(w, e.z, part.z);
                                part.w = fmaf(w, e.w, part.w);
                            }
                        }
                    } else {
                        for (int dy = 0; dy < 5; ++dy) {
                            int iy = by + dy - 2;
                            if ((unsigned)iy >= (unsigned)DIM) continue;
                            float wxy = wx * t5[dy];
                            for (int dz = 0; dz < 5; ++dz) {
                                int iz = bz + dz - 2;
                                if ((unsigned)iz >= (unsigned)DIM) continue;
                                float w = wxy * t5[dz];
                                float4 e = src[flatb(ix, iy, iz)];
                                part.x = fmaf(w, e.x, part.x);
                                part.y = fmaf(w, e.y, part.y);
                                part.z = fmaf(w, e.z, part.z);
                                part.w = fmaf(w, e.w, part.w);
                            }
                        }
                    }
                }
            }
            sh[threadIdx.x] = part;
            __syncthreads();
            if (threadIdx.x < 64) {
                // finalize by wave 0; head-flag segmented dedup on target bin
                int item2 = ib * IPB + threadIdx.x;
                bool valid = (threadIdx.x < IPB) && (item2 < K);
                int bn = -1;
                float4 sv = make_float4(0.f, 0.f, 0.f, 0.f);
                if (valid) {
                    int base5 = threadIdx.x * 5;
                    float4 a0 = sh[base5 + 0], a1 = sh[base5 + 1], a2 = sh[base5 + 2];
                    float4 a3 = sh[base5 + 3], a4 = sh[base5 + 4];
                    float sx = a0.x + a1.x + a2.x + a3.x + a4.x;
                    float sy = a0.y + a1.y + a2.y + a3.y + a4.y;
                    float sz = a0.z + a1.z + a2.z + a3.z + a4.z;
                    float sc = a0.w + a1.w + a2.w + a3.w + a4.w;
                    int b = list[item2];
                    float W = src[b].w;     // center count (occupied => sc>0)
                    float4 np = make_float4(sx / sc, sy / sc, sz / sc, W);
                    REo[item2] = np;
                    IDXo[b] = item2;
                    if (eposInit) eposInit[item2] = np;
                    if (!lastStep) {
                        bn = flatb(binf(np.x), binf(np.y), binf(np.z));
                        sv = make_float4(W * np.x, W * np.y, W * np.z, W);
                    }
                }
                if (!lastStep) {
                    // run heads: first lane or key differs from previous lane
                    int pbn = __shfl_up(bn, 1, 64);
                    unsigned f = (threadIdx.x == 0 || pbn != bn) ? 1u : 0u;
                    // leader = run end (next lane is a head, or last lane)
                    unsigned nf = __shfl_down(f, 1, 64);
                    bool leader = valid && (threadIdx.x == 63 || nf != 0u);
                    // flagged Hillis-Steele segmented inclusive sum
                    #pragma unroll
                    for (int off = 1; off < 64; off <<= 1) {
                        float ox = __shfl_up(sv.x, off, 64);
                        float oy = __shfl_up(sv.y, off, 64);
                        float oz = __shfl_up(sv.z, off, 64);
                        float ow = __shfl_up(sv.w, off, 64);
                        unsigned of = __shfl_up(f, off, 64);
                        if ((int)threadIdx.x >= off) {
                            if (!f) { sv.x += ox; sv.y += oy; sv.z += oz; sv.w += ow; }
                            f |= of;
                        }
                    }
                    if (leader) {
                        float* cell = (float*)&tgt[bn];
                        pk_add(cell + 0, sv.x, sv.y);
                        pk_add(cell + 2, sv.z, sv.w);
                        atomicOr(&clT[(unsigned)bn >> 5], 1u << (bn & 31));
                    }
                }
            }
            __syncthreads();    // sh reuse
        }
    } else {
        // ---------------- misc blocks ----------------
        int U = (updS > 0) ? (X ? n : *pM0) : 0;
        int CL = clearList ? *pKc : 0;
        int total = U + CL;
        bool done = false;
        if (updS > 1) {
            for (int t = 1; t < updS; ++t) done |= (notConv[t] == 0u);
        }
        int stride = (NF - BC) * blockDim.x;
        for (int idx = (blockIdx.x - BC) * blockDim.x + threadIdx.x; idx < total;
             idx += stride) {
            if (idx < U) {
                int e = idx;
                if (X) {  // per-point step-1 convergence via PIdx
                    float x = X[3 * e + 0], y = X[3 * e + 1], z = X[3 * e + 2];
                    float4 rr = REp[PIdx[e]];
                    float ex = rr.x - x, ey = rr.y - y, ez = rr.z - z;
                    moved |= (fmaf(ex, ex, fmaf(ey, ey, ez * ez)) > TOL2);
                } else if (!done) {  // per-entry update to step-updS position
                    float4 p = epos[e];
                    int j = IDXp[flatb(binf(p.x), binf(p.y), binf(p.z))];
                    float4 rr = REp[j];
                    float ex = rr.x - p.x, ey = rr.y - p.y, ez = rr.z - p.z;
                    moved |= (fmaf(ex, ex, fmaf(ey, ey, ez * ez)) > TOL2);
                    epos[e] = make_float4(rr.x, rr.y, rr.z, p.w);
                }
            } else {
                clearGrid[clearList[idx - U]] = make_float4(0.f, 0.f, 0.f, 0.f);
            }
        }
    }
    if (moved) sFlag = 1;
    __syncthreads();
    if (threadIdx.x == 0 && updS > 0 && sFlag) notConv[updS] = 1u;
}

// ---- finalize: per-entry final position table fpos[e] ----
__launch_bounds__(BLK)
__global__ void k_fin(const float4* __restrict__ REa, const int* __restrict__ IDXa,
                      const float4* __restrict__ epos, const int* __restrict__ pM0,
                      const unsigned* __restrict__ notConv, float4* __restrict__ fpos) {
    int M0 = *pM0;
    bool done = false;
    for (int t = 1; t <= 4; ++t) done |= (notConv[t] == 0u);
    for (int e = blockIdx.x * blockDim.x + threadIdx.x; e < M0;
         e += gridDim.x * blockDim.x) {
        float4 p = epos[e];
        if (!done) {
            float4 rr = REa[IDXa[flatb(binf(p.x), binf(p.y), binf(p.z))]];
            p.x = rr.x; p.y = rr.y; p.z = rr.z;
        }
        fpos[e] = p;
    }
}

// ---- per-point output: single gather through fpos via PIdx ----
__global__ void k_map(const int* __restrict__ PIdx, int n, const float4* __restrict__ fpos,
                      float* __restrict__ out) {
    int i = blockIdx.x * blockDim.x + threadIdx.x;
    if (i >= n) return;
    float4 p = fpos[PIdx[i]];
    out[3 * i + 0] = p.x;
    out[3 * i + 1] = p.y;
    out[3 * i + 2] = p.z;
}

extern "C" void kernel_launch(void* const* d_in, const int* in_sizes, int n_in,
                              void* d_out, int out_size, void* d_ws, size_t ws_size,
                              hipStream_t stream) {
    const float* X = (const float*)d_in[0];
    int n = in_sizes[0] / 3;

    char* ws = (char*)d_ws;
    int*      cnt     = (int*)ws;        // cnt[1..5] list sizes
    unsigned* notConv = (unsigned*)(ws + 32);
    size_t mB = (size_t)CLW * 4;
    size_t gB = (size_t)CELLS * 16;
    unsigned* m0 = (unsigned*)(ws + 256);
    unsigned* m1 = (unsigned*)(ws + 256 + mB);
    float4* A = (float4*)(ws + 256 + 2 * mB);
    float4* B = (float4*)((char*)A + gB);
    float4* C = (float4*)((char*)B + gB);
    int* IDXa = (int*)((char*)C + gB);
    int* IDXb = IDXa + CELLS;
    float4* REa  = (float4*)(IDXb + CELLS);
    float4* REb  = REa + n;
    float4* epos = REb + n;
    int* E0   = (int*)(epos + n);
    int* La   = E0 + n;
    int* Lb   = La + n;
    int* Lc   = Lb + n;
    int* Ld   = Lc + n;
    int* PIdx = Ld + n;
    float4* bucket = (float4*)(PIdx + n);
    int* blockHist = (int*)(bucket + n);
    int* regionPS  = blockHist + NB_A * NREG;

    // meta + masks only (A,B zeroed in histA, C in scatterA)
    hipMemsetAsync(ws, 0, 256 + 2 * mB, stream);

    const int NCM = (CLW + BLK - 1) / BLK;   // compactM blocks

    k_histA<<<NB_A, BLK, 0, stream>>>(X, n, blockHist, A, B);
    k_colscan<<<NREG / BLK, BLK, 0, stream>>>(blockHist, regionPS);
    k_regprefix<<<1, 1024, 0, stream>>>(regionPS);
    k_scatterA<<<NB_A, BLK, 0, stream>>>(X, n, blockHist, regionPS, bucket, C);
    k_binB<<<NREG, BLK, 0, stream>>>(bucket, regionPS, A, E0, PIdx, &cnt[1]);

    // F1: conv A/E0 -> REa/IDXa (+epos init); scatter->B claim m0
    k_fused<<<NF, BLK, 0, stream>>>(A, E0, &cnt[1], REa, IDXa, epos,
                                    B, m0,
                                    0, nullptr, n, nullptr, nullptr, nullptr, nullptr,
                                    nullptr, notConv, nullptr, nullptr, nullptr, 0);
    k_compactM<<<NCM, BLK, 0, stream>>>(m0, La, &cnt[2]);
    // F2: conv B/La -> REb/IDXb; scatter->C claim m1; upd1 via PIdx (REa); clear A via E0
    k_fused<<<NF, BLK, 0, stream>>>(B, La, &cnt[2], REb, IDXb, nullptr,
                                    C, m1,
                                    1, X, n, PIdx, REa, IDXa, &cnt[1], nullptr,
                                    notConv, E0, &cnt[1], A, 0);
    k_compactM<<<NCM, BLK, 0, stream>>>(m1, Lb, &cnt[3]);
    // F3: conv C/Lb -> REa/IDXa; scatter->A claim m0; upd2 (REb/IDXb); clear B via La
    k_fused<<<NF, BLK, 0, stream>>>(C, Lb, &cnt[3], REa, IDXa, nullptr,
                                    A, m0,
                                    2, nullptr, n, nullptr, REb, IDXb, &cnt[1], epos,
                                    notConv, La, &cnt[2], B, 0);
    k_compactM<<<NCM, BLK, 0, stream>>>(m0, Lc, &cnt[4]);
    // F4: conv A/Lc -> REb/IDXb; scatter->B claim m1; upd3 (REa/IDXa)
    k_fused<<<NF, BLK, 0, stream>>>(A, Lc, &cnt[4], REb, IDXb, nullptr,
                                    B, m1,
                                    3, nullptr, n, nullptr, REa, IDXa, &cnt[1], epos,
                                    notConv, nullptr, nullptr, nullptr, 0);
    k_compactM<<<NCM, BLK, 0, stream>>>(m1, Ld, &cnt[5]);
    // F5: conv B/Ld -> REa/IDXa (conv only); upd4 (REb/IDXb)
    k_fused<<<NF, BLK, 0, stream>>>(B, Ld, &cnt[5], REa, IDXa, nullptr,
                                    nullptr, nullptr,
                                    4, nullptr, n, nullptr, REb, IDXb, &cnt[1], epos,
                                    notConv, nullptr, nullptr, nullptr, 1);

    k_fin<<<256, BLK, 0, stream>>>(REa, IDXa, epos, &cnt[1], notConv, REb);
    k_map<<<(n + BLK - 1) / BLK, BLK, 0, stream>>>(PIdx, n, REb, (float*)d_out);
}